// Round 6
// baseline (1114.571 us; speedup 1.0000x reference)
//
#include <hip/hip_runtime.h>

#define NH 6
#define NTOK 49
#define CDIM 192
#define NWIN 1024
#define SCALE 0.17677669529663687f

typedef __bf16 bf16x8 __attribute__((ext_vector_type(8)));
typedef float f32x4 __attribute__((ext_vector_type(4)));
typedef unsigned short u16;
typedef unsigned int u32;

__device__ __forceinline__ u16 bfr(float x) { return __builtin_bit_cast(u16, (__bf16)x); }

__global__ void build_wb(const float* __restrict__ w, u16* __restrict__ wb) {
    int i = blockIdx.x * 256 + threadIdx.x;
    if (i < CDIM * CDIM) wb[i] = bfr(w[i]);
}

// ---------------- Kernel A: attention -> x in MFMA-fragment-tiled layout ----------------
// One block per window, 256 thr = 4 waves, 8 blocks/CU (VGPR<=64, LDS 18432).
// xt layout: [win][wv(4)][ks(6)][lane(64)][8] bf16 -- both the store here and the
// A-fragment load in proj are lane*16B contiguous (fully coalesced).
__global__ __launch_bounds__(256, 8)
void attn_x(const float* __restrict__ qkv, const int* __restrict__ rpi,
            const float* __restrict__ mask, const float* __restrict__ bias_table,
            u16* __restrict__ xt) {
    __shared__ u16 vT_s[2][32][72];  // V^T bf16 [d][n], row 144B
    __shared__ u16 p_s[64][72];      // P / x_h staging, wave-private 16-row stripes

    const int tid = threadIdx.x;
    const int b = blockIdx.x;
    const int wn = b & (NWIN - 1);
    const int wv = tid >> 6;
    const int lane = tid & 63;
    const int lg = lane >> 4;
    const int lc = lane & 15;

    const float* qkvb = qkv + (size_t)b * (NTOK * 3 * CDIM);
    const float* mrow = mask + (size_t)wn * (NTOK * NTOK);
    const f32x4 fzero = {0.f, 0.f, 0.f, 0.f};

    // V staging distribution: item idx in [0,392): n=idx>>3, f=idx&7
    const int n0 = tid >> 3, f0 = tid & 7;
    const bool s1 = tid < 136;
    const int n1 = (tid + 256) >> 3, f1 = (tid + 256) & 7;
    const float* vb0 = qkvb + n0 * 576 + 2 * CDIM + f0 * 4;
    const float* vb1 = qkvb + n1 * 576 + 2 * CDIM + f1 * 4;

    // per-lane Q row pointer (clamped; pad rows masked later)
    const int qrow = (16 * wv + lc < NTOK) ? 16 * wv + lc : NTOK - 1;
    const float* qptr = qkvb + (size_t)qrow * 576 + 8 * lg;
    // per-lane K row pointers for the 4 column tiles
    const float* kptr[4];
#pragma unroll
    for (int t = 0; t < 4; ++t) {
        const int krow = (16 * t + lc < NTOK) ? 16 * t + lc : NTOK - 1;
        kptr[t] = qkvb + (size_t)krow * 576 + CDIM + 8 * lg;
    }

    // x store: fragment-tiled, bijective lane permutation, 16B/lane contiguous
    u16* xst = xt + (size_t)b * (4 * 6 * 64 * 8) + wv * (6 * 64 * 8)
             + (((lane & 3) << 4) | (lane >> 2)) * 8;

    // ---- hoist rpi/mask: 8 packed index regs + 2 bitmask regs ----
    u32 bidx2[8];
    u32 mbits = 0, vbits = 0;
#pragma unroll
    for (int r = 0; r < 4; ++r) {
        const int i = 16 * wv + 4 * lg + r;
#pragma unroll
        for (int t = 0; t < 4; ++t) {
            const int j = 16 * t + lc;
            const int idx = r * 4 + t;
            const bool valid = (i < NTOK) && (j < NTOK);
            const int ij = valid ? i * NTOK + j : 0;
            const u32 bi = (u32)(rpi[ij] * NH);  // < 1014, fits 16 bits
            if (idx & 1) bidx2[idx >> 1] |= bi << 16; else bidx2[idx >> 1] = bi;
            const float mv = valid ? mrow[ij] : 0.f;
            if (!valid) vbits |= 1u << idx;
            if (mv < -50.f) mbits |= 1u << idx;
        }
    }

    // ---- zero vT pad cols 49..63 once (both buffers; never rewritten) ----
    for (int idx = tid; idx < 512; idx += 256) {
        const int d = idx >> 4, m = idx & 15;
        if (m) { vT_s[0][d][48 + m] = 0; vT_s[1][d][48 + m] = 0; }
    }

    // ---- prefetch + stage V for h=0 ----
    float4 vp0 = *reinterpret_cast<const float4*>(vb0);
    float4 vp1 = {0, 0, 0, 0};
    if (s1) vp1 = *reinterpret_cast<const float4*>(vb1);
    {
        const int d0 = f0 * 4;
        vT_s[0][d0 + 0][n0] = bfr(vp0.x); vT_s[0][d0 + 1][n0] = bfr(vp0.y);
        vT_s[0][d0 + 2][n0] = bfr(vp0.z); vT_s[0][d0 + 3][n0] = bfr(vp0.w);
        if (s1) {
            const int d1 = f1 * 4;
            vT_s[0][d1 + 0][n1] = bfr(vp1.x); vT_s[0][d1 + 1][n1] = bfr(vp1.y);
            vT_s[0][d1 + 2][n1] = bfr(vp1.z); vT_s[0][d1 + 3][n1] = bfr(vp1.w);
        }
    }
    __syncthreads();

    for (int h = 0; h < NH; ++h) {
        const int cur = h & 1;

        // ---- Q fragment direct ----
        const float4 qA = *reinterpret_cast<const float4*>(qptr + h * 32);
        const float4 qB = *reinterpret_cast<const float4*>(qptr + h * 32 + 4);
        bf16x8 aq;
        aq[0] = (__bf16)(qA.x * SCALE); aq[1] = (__bf16)(qA.y * SCALE);
        aq[2] = (__bf16)(qA.z * SCALE); aq[3] = (__bf16)(qA.w * SCALE);
        aq[4] = (__bf16)(qB.x * SCALE); aq[5] = (__bf16)(qB.y * SCALE);
        aq[6] = (__bf16)(qB.z * SCALE); aq[7] = (__bf16)(qB.w * SCALE);

        // ---- K fragments direct + QK^T ----
        f32x4 acc[4];
#pragma unroll
        for (int t = 0; t < 4; ++t) {
            const float4 kA = *reinterpret_cast<const float4*>(kptr[t] + h * 32);
            const float4 kB = *reinterpret_cast<const float4*>(kptr[t] + h * 32 + 4);
            bf16x8 bk;
            bk[0] = (__bf16)kA.x; bk[1] = (__bf16)kA.y; bk[2] = (__bf16)kA.z; bk[3] = (__bf16)kA.w;
            bk[4] = (__bf16)kB.x; bk[5] = (__bf16)kB.y; bk[6] = (__bf16)kB.z; bk[7] = (__bf16)kB.w;
            acc[t] = __builtin_amdgcn_mfma_f32_16x16x32_bf16(aq, bk, fzero, 0, 0, 0);
        }

        // ---- issue V prefetch for h+1 (hides under softmax+PV) ----
        if (h + 1 < NH) {
            vp0 = *reinterpret_cast<const float4*>(vb0 + (h + 1) * 32);
            if (s1) vp1 = *reinterpret_cast<const float4*>(vb1 + (h + 1) * 32);
        }

        // ---- softmax (rows wave-private; pad rows -> 1/16 each, finite) ----
#pragma unroll
        for (int r = 0; r < 4; ++r) {
            const int i = 16 * wv + 4 * lg + r;
            float vals[4];
#pragma unroll
            for (int t = 0; t < 4; ++t) {
                const int idx = r * 4 + t;
                const u32 bp = bidx2[idx >> 1];
                const int bi = (idx & 1) ? (int)(bp >> 16) : (int)(bp & 0xFFFFu);
                const float bias = bias_table[bi + h];
                float v = acc[t][r] + bias + (((mbits >> idx) & 1u) ? -100.f : 0.f);
                vals[t] = ((vbits >> idx) & 1u) ? -1e30f : v;
            }
            float m = fmaxf(fmaxf(vals[0], vals[1]), fmaxf(vals[2], vals[3]));
#pragma unroll
            for (int off = 1; off < 16; off <<= 1) m = fmaxf(m, __shfl_xor(m, off, 16));
            float e[4], s = 0.f;
#pragma unroll
            for (int t = 0; t < 4; ++t) { e[t] = __expf(vals[t] - m); s += e[t]; }
#pragma unroll
            for (int off = 1; off < 16; off <<= 1) s += __shfl_xor(s, off, 16);
            const float rs = 1.0f / s;
#pragma unroll
            for (int t = 0; t < 4; ++t)
                p_s[i][16 * t + lc] = bfr(e[t] * rs);
        }

        // ---- PV: x_h[16x32] per wave ----
        f32x4 xacc[2] = {fzero, fzero};
#pragma unroll
        for (int ks = 0; ks < 2; ++ks) {
            const bf16x8 pa = *reinterpret_cast<const bf16x8*>(&p_s[16 * wv + lc][32 * ks + 8 * lg]);
#pragma unroll
            for (int ct = 0; ct < 2; ++ct) {
                const bf16x8 vv = *reinterpret_cast<const bf16x8*>(&vT_s[cur][16 * ct + lc][32 * ks + 8 * lg]);
                xacc[ct] = __builtin_amdgcn_mfma_f32_16x16x32_bf16(pa, vv, xacc[ct], 0, 0, 0);
            }
        }

        // ---- stage V h+1 into other buffer ----
        if (h + 1 < NH) {
            const int nb = cur ^ 1;
            const int d0 = f0 * 4;
            vT_s[nb][d0 + 0][n0] = bfr(vp0.x); vT_s[nb][d0 + 1][n0] = bfr(vp0.y);
            vT_s[nb][d0 + 2][n0] = bfr(vp0.z); vT_s[nb][d0 + 3][n0] = bfr(vp0.w);
            if (s1) {
                const int d1 = f1 * 4;
                vT_s[nb][d1 + 0][n1] = bfr(vp1.x); vT_s[nb][d1 + 1][n1] = bfr(vp1.y);
                vT_s[nb][d1 + 2][n1] = bfr(vp1.z); vT_s[nb][d1 + 3][n1] = bfr(vp1.w);
            }
        }

        // ---- x_h -> p_s stripe (wave-private), coalesced 16B/lane store to xt ----
#pragma unroll
        for (int ct = 0; ct < 2; ++ct)
#pragma unroll
            for (int r = 0; r < 4; ++r)
                p_s[16 * wv + 4 * lg + r][16 * ct + lc] = bfr(xacc[ct][r]);
        {
            const bf16x8 xv = *reinterpret_cast<const bf16x8*>(&p_s[16 * wv + (lane >> 2)][(lane & 3) * 8]);
            *reinterpret_cast<bf16x8*>(xst + h * (64 * 8)) = xv;
        }

        if (h + 1 < NH) __syncthreads();
    }
}

// ---------------- Kernel B: out = x @ W^T + b, 2 col-halves/window, 8 blocks/CU ----------------
__global__ __launch_bounds__(256, 8)
void proj_gemm(const u16* __restrict__ xt, const u16* __restrict__ wb,
               const float* __restrict__ pb, float* __restrict__ out) {
    const int w = blockIdx.x >> 1;
    const int ch = blockIdx.x & 1;
    const int tid = threadIdx.x;
    const int wv = tid >> 6, lane = tid & 63, lg = lane >> 4, lc = lane & 15;
    const f32x4 fzero = {0.f, 0.f, 0.f, 0.f};

    const u16* xb = xt + (size_t)w * (4 * 6 * 64 * 8) + wv * (6 * 64 * 8) + lane * 8;

    // A-fragments: fully coalesced (lane*16B), rows 16wv..16wv+15, all K=192
    bf16x8 af[6];
#pragma unroll
    for (int ks = 0; ks < 6; ++ks)
        af[ks] = *reinterpret_cast<const bf16x8*>(xb + ks * (64 * 8));

    f32x4 pacc[6];
#pragma unroll
    for (int ct = 0; ct < 6; ++ct) pacc[ct] = fzero;

#pragma unroll
    for (int ct = 0; ct < 6; ++ct) {
        const int c = 96 * ch + 16 * ct + lc;
#pragma unroll
        for (int ks = 0; ks < 6; ++ks) {
            const bf16x8 bw = *reinterpret_cast<const bf16x8*>(wb + c * CDIM + ks * 32 + 8 * lg);
            pacc[ct] = __builtin_amdgcn_mfma_f32_16x16x32_bf16(af[ks], bw, pacc[ct], 0, 0, 0);
        }
    }

#pragma unroll
    for (int ct = 0; ct < 6; ++ct) {
        const int c = 96 * ch + 16 * ct + lc;
        const float bb = pb[c];
#pragma unroll
        for (int r = 0; r < 4; ++r) {
            const int i = 16 * wv + 4 * lg + r;
            if (i < NTOK)
                out[((size_t)w * NTOK + i) * CDIM + c] = pacc[ct][r] + bb;
        }
    }
}

// ---------------- Fallback: R3's fused kernel (proven), if ws too small ----------------
__global__ __launch_bounds__(256, 4)
void swin_attn_fused(const float* __restrict__ qkv, const int* __restrict__ rpi,
                     const float* __restrict__ mask, const float* __restrict__ bias_table,
                     const u16* __restrict__ wb, const float* __restrict__ proj_b,
                     float* __restrict__ out) {
    __shared__ u16 vT_s[32][72];
    __shared__ u16 p_s[64][72];
    __shared__ u16 xb_s[64][200];

    const int tid = threadIdx.x;
    const int b = blockIdx.x;
    const int wn = b & (NWIN - 1);
    const int wv = tid >> 6;
    const int lane = tid & 63;
    const int lg = lane >> 4;
    const int lc = lane & 15;

    const float* qkvb = qkv + (size_t)b * (NTOK * 3 * CDIM);
    const float* mrow = mask + (size_t)wn * (NTOK * NTOK);
    const f32x4 fzero = {0.f, 0.f, 0.f, 0.f};

    float madd[4][4];
    int bidx[4][4];
#pragma unroll
    for (int r = 0; r < 4; ++r) {
        const int i = 16 * wv + 4 * lg + r;
#pragma unroll
        for (int t = 0; t < 4; ++t) {
            const int j = 16 * t + lc;
            const bool valid = (i < NTOK) && (j < NTOK);
            const int ij = valid ? i * NTOK + j : 0;
            madd[r][t] = valid ? mrow[ij] : -1e30f;
            bidx[r][t] = rpi[ij] * NH;
        }
    }
    for (int idx = tid; idx < 512; idx += 256) {
        const int d = idx >> 4, m = idx & 15;
        if (m) vT_s[d][48 + m] = 0;
    }
    float4 vp0 = {0, 0, 0, 0}, vp1 = {0, 0, 0, 0};
    {
        const int n = tid >> 3, f = tid & 7;
        vp0 = *reinterpret_cast<const float4*>(qkvb + n * 576 + 2 * CDIM + f * 4);
    }
    if (tid + 256 < 392) {
        const int idx = tid + 256, n = idx >> 3, f = idx & 7;
        vp1 = *reinterpret_cast<const float4*>(qkvb + n * 576 + 2 * CDIM + f * 4);
    }

    for (int h = 0; h < NH; ++h) {
        __syncthreads();
        {
            const int n = tid >> 3, d = (tid & 7) * 4;
            vT_s[d + 0][n] = bfr(vp0.x); vT_s[d + 1][n] = bfr(vp0.y);
            vT_s[d + 2][n] = bfr(vp0.z); vT_s[d + 3][n] = bfr(vp0.w);
        }
        if (tid + 256 < 392) {
            const int idx = tid + 256, n = idx >> 3, d = (idx & 7) * 4;
            vT_s[d + 0][n] = bfr(vp1.x); vT_s[d + 1][n] = bfr(vp1.y);
            vT_s[d + 2][n] = bfr(vp1.z); vT_s[d + 3][n] = bfr(vp1.w);
        }
        __syncthreads();
        if (h + 1 < NH) {
            {
                const int n = tid >> 3, f = tid & 7;
                vp0 = *reinterpret_cast<const float4*>(qkvb + n * 576 + 2 * CDIM + (h + 1) * 32 + f * 4);
            }
            if (tid + 256 < 392) {
                const int idx = tid + 256, n = idx >> 3, f = idx & 7;
                vp1 = *reinterpret_cast<const float4*>(qkvb + n * 576 + 2 * CDIM + (h + 1) * 32 + f * 4);
            }
        }
        const int qrow = (16 * wv + lc < NTOK) ? 16 * wv + lc : NTOK - 1;
        const float* qp = qkvb + (size_t)qrow * 576 + h * 32 + 8 * lg;
        const float4 qa4 = *reinterpret_cast<const float4*>(qp);
        const float4 qb4 = *reinterpret_cast<const float4*>(qp + 4);
        bf16x8 aq;
        aq[0] = (__bf16)(qa4.x * SCALE); aq[1] = (__bf16)(qa4.y * SCALE);
        aq[2] = (__bf16)(qa4.z * SCALE); aq[3] = (__bf16)(qa4.w * SCALE);
        aq[4] = (__bf16)(qb4.x * SCALE); aq[5] = (__bf16)(qb4.y * SCALE);
        aq[6] = (__bf16)(qb4.z * SCALE); aq[7] = (__bf16)(qb4.w * SCALE);
        f32x4 acc[4];
#pragma unroll
        for (int t = 0; t < 4; ++t) {
            const int krow = (16 * t + lc < NTOK) ? 16 * t + lc : NTOK - 1;
            const float* kp = qkvb + (size_t)krow * 576 + CDIM + h * 32 + 8 * lg;
            const float4 ka = *reinterpret_cast<const float4*>(kp);
            const float4 kb = *reinterpret_cast<const float4*>(kp + 4);
            bf16x8 bk;
            bk[0] = (__bf16)ka.x; bk[1] = (__bf16)ka.y; bk[2] = (__bf16)ka.z; bk[3] = (__bf16)ka.w;
            bk[4] = (__bf16)kb.x; bk[5] = (__bf16)kb.y; bk[6] = (__bf16)kb.z; bk[7] = (__bf16)kb.w;
            acc[t] = __builtin_amdgcn_mfma_f32_16x16x32_bf16(aq, bk, fzero, 0, 0, 0);
        }
#pragma unroll
        for (int r = 0; r < 4; ++r) {
            const int i = 16 * wv + 4 * lg + r;
            float vals[4];
#pragma unroll
            for (int t = 0; t < 4; ++t)
                vals[t] = acc[t][r] + bias_table[bidx[r][t] + h] + madd[r][t];
            float m = fmaxf(fmaxf(vals[0], vals[1]), fmaxf(vals[2], vals[3]));
#pragma unroll
            for (int off = 1; off < 16; off <<= 1) m = fmaxf(m, __shfl_xor(m, off, 16));
            float e[4], s = 0.f;
#pragma unroll
            for (int t = 0; t < 4; ++t) { e[t] = __expf(vals[t] - m); s += e[t]; }
#pragma unroll
            for (int off = 1; off < 16; off <<= 1) s += __shfl_xor(s, off, 16);
            const float rs = 1.0f / s;
#pragma unroll
            for (int t = 0; t < 4; ++t)
                p_s[i][16 * t + lc] = bfr(e[t] * rs);
        }
        f32x4 xacc[2] = {fzero, fzero};
#pragma unroll
        for (int ks = 0; ks < 2; ++ks) {
            const bf16x8 pa = *reinterpret_cast<const bf16x8*>(&p_s[16 * wv + lc][32 * ks + 8 * lg]);
#pragma unroll
            for (int ct = 0; ct < 2; ++ct) {
                const bf16x8 vv = *reinterpret_cast<const bf16x8*>(&vT_s[16 * ct + lc][32 * ks + 8 * lg]);
                xacc[ct] = __builtin_amdgcn_mfma_f32_16x16x32_bf16(pa, vv, xacc[ct], 0, 0, 0);
            }
        }
#pragma unroll
        for (int ct = 0; ct < 2; ++ct)
#pragma unroll
            for (int r = 0; r < 4; ++r)
                xb_s[16 * wv + 4 * lg + r][h * 32 + 16 * ct + lc] = bfr(xacc[ct][r]);
    }
    __syncthreads();
    f32x4 pacc[3][4];
#pragma unroll
    for (int ct = 0; ct < 3; ++ct)
#pragma unroll
        for (int rt = 0; rt < 4; ++rt) pacc[ct][rt] = fzero;
#pragma unroll
    for (int ks = 0; ks < 6; ++ks) {
        bf16x8 af[4];
#pragma unroll
        for (int rt = 0; rt < 4; ++rt)
            af[rt] = *reinterpret_cast<const bf16x8*>(&xb_s[16 * rt + lc][32 * ks + 8 * lg]);
#pragma unroll
        for (int ct = 0; ct < 3; ++ct) {
            const int c = 48 * wv + 16 * ct + lc;
            const bf16x8 bw = *reinterpret_cast<const bf16x8*>(wb + c * CDIM + 32 * ks + 8 * lg);
#pragma unroll
            for (int rt = 0; rt < 4; ++rt)
                pacc[ct][rt] = __builtin_amdgcn_mfma_f32_16x16x32_bf16(af[rt], bw, pacc[ct][rt], 0, 0, 0);
        }
    }
#pragma unroll
    for (int ct = 0; ct < 3; ++ct) {
        const int c = 48 * wv + 16 * ct + lc;
        const float pb = proj_b[c];
#pragma unroll
        for (int rt = 0; rt < 4; ++rt) {
#pragma unroll
            for (int r = 0; r < 4; ++r) {
                const int i = 16 * rt + 4 * lg + r;
                if (i < NTOK)
                    out[(size_t)b * (NTOK * CDIM) + i * CDIM + c] = pacc[ct][rt][r] + pb;
            }
        }
    }
}

extern "C" void kernel_launch(void* const* d_in, const int* in_sizes, int n_in,
                              void* d_out, int out_size, void* d_ws, size_t ws_size,
                              hipStream_t stream) {
    const float* qkv        = (const float*)d_in[0];
    const int*   rpi        = (const int*)d_in[1];
    const float* mask       = (const float*)d_in[2];
    const float* bias_table = (const float*)d_in[3];
    const float* proj_w     = (const float*)d_in[4];
    const float* proj_b     = (const float*)d_in[5];
    float* out = (float*)d_out;

    u16* wb = (u16*)d_ws;                         // bf16 W, 73728 B
    u16* xt = (u16*)((char*)d_ws + 131072);       // fragment-tiled x, nblk*12288*2 B

    const int nblk = in_sizes[0] / (NTOK * 3 * CDIM);  // 8192 windows
    const size_t need = 131072 + (size_t)nblk * 12288 * 2;

    build_wb<<<(CDIM * CDIM + 255) / 256, 256, 0, stream>>>(proj_w, wb);
    if (ws_size >= need) {
        attn_x<<<nblk, 256, 0, stream>>>(qkv, rpi, mask, bias_table, xt);
        proj_gemm<<<nblk * 2, 256, 0, stream>>>(xt, wb, proj_b, out);
    } else {
        swin_attn_fused<<<nblk, 256, 0, stream>>>(qkv, rpi, mask, bias_table, wb, proj_b, out);
    }
}

// Round 7
// 599.536 us; speedup vs baseline: 1.8591x; 1.8591x over previous
//
#include <hip/hip_runtime.h>

#define NH 6
#define NTOK 49
#define CDIM 192
#define NWIN 1024
#define SCALE 0.17677669529663687f

typedef __bf16 bf16x8 __attribute__((ext_vector_type(8)));
typedef float f32x4 __attribute__((ext_vector_type(4)));
typedef unsigned short u16;
typedef unsigned int u32;

__device__ __forceinline__ u16 bfr(float x) { return __builtin_bit_cast(u16, (__bf16)x); }

__global__ void build_wb(const float* __restrict__ w, u16* __restrict__ wb) {
    int i = blockIdx.x * 256 + threadIdx.x;
    if (i < CDIM * CDIM) wb[i] = bfr(w[i]);
}

// Fused window attention + proj. One block per window, 256 thr = 4 waves,
// __launch_bounds__(256,4): 4 waves/SIMD is the proven ceiling (R6: (256,8)
// -> 32 VGPR -> spill storm). Chain-shortening instead:
//  - K staged in LDS (stage floats prefetched 1 head ahead): QK^T reads are
//    ~120cyc ds_read_b128 instead of ~900cyc cold-HBM loads.
//  - Q prefetched 1 head ahead into regs.
//  - x_h held as register A-fragments af[0..5] (transposed via the wave-private
//    p_s stripe) -> no xb_s LDS, no proj barrier; pacc[12] (48 AGPR) only live
//    AFTER the head loop (disjoint from loop pressure, unlike R4).
// LDS = 5120(k_s) + 4608(vT) + 9216(p_s) = 18944 B.
__global__ __launch_bounds__(256, 4)
void swin_fused(const float* __restrict__ qkv, const int* __restrict__ rpi,
                const float* __restrict__ mask, const float* __restrict__ bias_table,
                const u16* __restrict__ wb, const float* __restrict__ proj_b,
                float* __restrict__ out) {
    __shared__ u16 k_s[64][40];   // K bf16; rows 49..63 garbage (vbits kills them pre-exp)
    __shared__ u16 vT_s[32][72];  // V^T bf16 [d][n]; pad cols zeroed once
    __shared__ u16 p_s[64][72];   // P then x_h; wave-private 16-row stripes

    const int tid = threadIdx.x;
    const int b = blockIdx.x;
    const int wn = b & (NWIN - 1);
    const int wv = tid >> 6;
    const int lane = tid & 63;
    const int lg = lane >> 4;
    const int lc = lane & 15;

    const float* qkvb = qkv + (size_t)b * (NTOK * 3 * CDIM);
    const float* mrow = mask + (size_t)wn * (NTOK * NTOK);
    const f32x4 fzero = {0.f, 0.f, 0.f, 0.f};

    // staging distribution: item idx in [0,392): n=idx>>3, f=idx&7
    const int n0 = tid >> 3, f0 = tid & 7;
    const bool s1 = tid < 136;
    const int n1 = (tid + 256) >> 3, f1 = (tid + 256) & 7;
    const float* kb0 = qkvb + n0 * 576 + CDIM + f0 * 4;
    const float* vb0 = qkvb + n0 * 576 + 2 * CDIM + f0 * 4;
    const float* kb1 = qkvb + n1 * 576 + CDIM + f1 * 4;
    const float* vb1 = qkvb + n1 * 576 + 2 * CDIM + f1 * 4;

    // per-lane Q row pointer (clamped; pad rows masked later)
    const int qrow = (16 * wv + lc < NTOK) ? 16 * wv + lc : NTOK - 1;
    const float* qptr = qkvb + (size_t)qrow * 576 + 8 * lg;

    // ---- issue h=0 loads (latency overlaps bidx/mask setup below) ----
    float4 kp0 = *reinterpret_cast<const float4*>(kb0);
    float4 vp0 = *reinterpret_cast<const float4*>(vb0);
    float4 kp1 = {0, 0, 0, 0}, vp1 = {0, 0, 0, 0};
    if (s1) {
        kp1 = *reinterpret_cast<const float4*>(kb1);
        vp1 = *reinterpret_cast<const float4*>(vb1);
    }
    float4 qfA = *reinterpret_cast<const float4*>(qptr);
    float4 qfB = *reinterpret_cast<const float4*>(qptr + 4);

    // ---- hoist rpi/mask: 8 packed index regs + 2 bitmask regs ----
    u32 bidx2[8];
    u32 mbits = 0, vbits = 0;
#pragma unroll
    for (int r = 0; r < 4; ++r) {
        const int i = 16 * wv + 4 * lg + r;
#pragma unroll
        for (int t = 0; t < 4; ++t) {
            const int j = 16 * t + lc;
            const int idx = r * 4 + t;
            const bool valid = (i < NTOK) && (j < NTOK);
            const int ij = valid ? i * NTOK + j : 0;
            const u32 bi = (u32)(rpi[ij] * NH);  // < 1014, fits 16 bits
            if (idx & 1) bidx2[idx >> 1] |= bi << 16; else bidx2[idx >> 1] = bi;
            const float mv = valid ? mrow[ij] : 0.f;
            if (!valid) vbits |= 1u << idx;
            if (mv < -50.f) mbits |= 1u << idx;
        }
    }

    // ---- zero vT pad cols 49..63 once (staging only rewrites cols 0..48) ----
    for (int idx = tid; idx < 512; idx += 256) {
        const int d = idx >> 4, m = idx & 15;
        if (m) vT_s[d][48 + m] = 0;
    }

    // ---- stage h=0 K and V ----
    {
        ushort4 ko;
        ko.x = bfr(kp0.x); ko.y = bfr(kp0.y); ko.z = bfr(kp0.z); ko.w = bfr(kp0.w);
        *reinterpret_cast<ushort4*>(&k_s[n0][f0 * 4]) = ko;
        const int d0 = f0 * 4;
        vT_s[d0 + 0][n0] = bfr(vp0.x); vT_s[d0 + 1][n0] = bfr(vp0.y);
        vT_s[d0 + 2][n0] = bfr(vp0.z); vT_s[d0 + 3][n0] = bfr(vp0.w);
        if (s1) {
            ushort4 k1;
            k1.x = bfr(kp1.x); k1.y = bfr(kp1.y); k1.z = bfr(kp1.z); k1.w = bfr(kp1.w);
            *reinterpret_cast<ushort4*>(&k_s[n1][f1 * 4]) = k1;
            const int d1 = f1 * 4;
            vT_s[d1 + 0][n1] = bfr(vp1.x); vT_s[d1 + 1][n1] = bfr(vp1.y);
            vT_s[d1 + 2][n1] = bfr(vp1.z); vT_s[d1 + 3][n1] = bfr(vp1.w);
        }
    }
    __syncthreads();

    bf16x8 af[NH];  // x_h A-fragments, filled per head (loop fully unrolled -> static idx)

#pragma unroll
    for (int h = 0; h < NH; ++h) {
        // ---- issue K/V stage-loads for h+1 (kp/vp regs are free: h's data
        //      was staged at the bottom of h-1) ----
        if (h + 1 < NH) {
            kp0 = *reinterpret_cast<const float4*>(kb0 + (h + 1) * 32);
            vp0 = *reinterpret_cast<const float4*>(vb0 + (h + 1) * 32);
            if (s1) {
                kp1 = *reinterpret_cast<const float4*>(kb1 + (h + 1) * 32);
                vp1 = *reinterpret_cast<const float4*>(vb1 + (h + 1) * 32);
            }
        }

        // ---- Q fragment from prefetched regs (waits only its own old vmcnt) ----
        bf16x8 aq;
        aq[0] = (__bf16)(qfA.x * SCALE); aq[1] = (__bf16)(qfA.y * SCALE);
        aq[2] = (__bf16)(qfA.z * SCALE); aq[3] = (__bf16)(qfA.w * SCALE);
        aq[4] = (__bf16)(qfB.x * SCALE); aq[5] = (__bf16)(qfB.y * SCALE);
        aq[6] = (__bf16)(qfB.z * SCALE); aq[7] = (__bf16)(qfB.w * SCALE);
        if (h + 1 < NH) {
            qfA = *reinterpret_cast<const float4*>(qptr + (h + 1) * 32);
            qfB = *reinterpret_cast<const float4*>(qptr + (h + 1) * 32 + 4);
        }

        // ---- QK^T: K from LDS (~120cyc) ----
        bf16x8 bk[4];
#pragma unroll
        for (int t = 0; t < 4; ++t)
            bk[t] = *reinterpret_cast<const bf16x8*>(&k_s[16 * t + lc][8 * lg]);

        // bias gather (L1-resident 4KB table) issued alongside the MFMAs
        float bias_v[4][4];
#pragma unroll
        for (int r = 0; r < 4; ++r)
#pragma unroll
            for (int t = 0; t < 4; ++t) {
                const int idx = r * 4 + t;
                const u32 bp = bidx2[idx >> 1];
                const int bi = (idx & 1) ? (int)(bp >> 16) : (int)(bp & 0xFFFFu);
                bias_v[r][t] = bias_table[bi + h];
            }

        f32x4 acc[4];
#pragma unroll
        for (int t = 0; t < 4; ++t)
            acc[t] = __builtin_amdgcn_mfma_f32_16x16x32_bf16(aq, bk[t], fzero, 0, 0, 0);

        // ---- softmax (rows wave-private) ----
#pragma unroll
        for (int r = 0; r < 4; ++r) {
            const int i = 16 * wv + 4 * lg + r;
            float vals[4];
#pragma unroll
            for (int t = 0; t < 4; ++t) {
                const int idx = r * 4 + t;
                float v = acc[t][r] + bias_v[r][t] + (((mbits >> idx) & 1u) ? -100.f : 0.f);
                vals[t] = ((vbits >> idx) & 1u) ? -1e30f : v;  // cndmask also kills NaN from pad-K
            }
            float m = fmaxf(fmaxf(vals[0], vals[1]), fmaxf(vals[2], vals[3]));
#pragma unroll
            for (int off = 1; off < 16; off <<= 1) m = fmaxf(m, __shfl_xor(m, off, 16));
            float e[4], s = 0.f;
#pragma unroll
            for (int t = 0; t < 4; ++t) { e[t] = __expf(vals[t] - m); s += e[t]; }
#pragma unroll
            for (int off = 1; off < 16; off <<= 1) s += __shfl_xor(s, off, 16);
            const float rs = 1.0f / s;
#pragma unroll
            for (int t = 0; t < 4; ++t)
                p_s[i][16 * t + lc] = bfr(e[t] * rs);
        }

        // ---- PV: x_h[16x32] per wave ----
        f32x4 xacc[2] = {fzero, fzero};
#pragma unroll
        for (int ks = 0; ks < 2; ++ks) {
            const bf16x8 pa = *reinterpret_cast<const bf16x8*>(&p_s[16 * wv + lc][32 * ks + 8 * lg]);
#pragma unroll
            for (int ct = 0; ct < 2; ++ct) {
                const bf16x8 vv = *reinterpret_cast<const bf16x8*>(&vT_s[16 * ct + lc][32 * ks + 8 * lg]);
                xacc[ct] = __builtin_amdgcn_mfma_f32_16x16x32_bf16(pa, vv, xacc[ct], 0, 0, 0);
            }
        }

        // ---- x_h C-layout -> A-fragment via wave-private p_s stripe (no barrier) ----
#pragma unroll
        for (int ct = 0; ct < 2; ++ct)
#pragma unroll
            for (int r = 0; r < 4; ++r)
                p_s[16 * wv + 4 * lg + r][16 * ct + lc] = bfr(xacc[ct][r]);
        af[h] = *reinterpret_cast<const bf16x8*>(&p_s[16 * wv + lc][8 * lg]);

        // ---- stage h+1 K/V (values loaded at top of this iter) ----
        if (h + 1 < NH) {
            __syncthreads();  // all waves done reading k_s/vT of head h
            ushort4 ko;
            ko.x = bfr(kp0.x); ko.y = bfr(kp0.y); ko.z = bfr(kp0.z); ko.w = bfr(kp0.w);
            *reinterpret_cast<ushort4*>(&k_s[n0][f0 * 4]) = ko;
            const int d0 = f0 * 4;
            vT_s[d0 + 0][n0] = bfr(vp0.x); vT_s[d0 + 1][n0] = bfr(vp0.y);
            vT_s[d0 + 2][n0] = bfr(vp0.z); vT_s[d0 + 3][n0] = bfr(vp0.w);
            if (s1) {
                ushort4 k1;
                k1.x = bfr(kp1.x); k1.y = bfr(kp1.y); k1.z = bfr(kp1.z); k1.w = bfr(kp1.w);
                *reinterpret_cast<ushort4*>(&k_s[n1][f1 * 4]) = k1;
                const int d1 = f1 * 4;
                vT_s[d1 + 0][n1] = bfr(vp1.x); vT_s[d1 + 1][n1] = bfr(vp1.y);
                vT_s[d1 + 2][n1] = bfr(vp1.z); vT_s[d1 + 3][n1] = bfr(vp1.w);
            }
            __syncthreads();  // k_s/vT for h+1 ready
        }
    }

    // ---- proj tail: out rows 16wv.., all 192 cols; pacc live only here ----
    f32x4 pacc[12];
#pragma unroll
    for (int ct = 0; ct < 12; ++ct) pacc[ct] = fzero;

#pragma unroll
    for (int ks = 0; ks < NH; ++ks) {
#pragma unroll
        for (int ct = 0; ct < 12; ++ct) {
            const bf16x8 bw = *reinterpret_cast<const bf16x8*>(wb + (16 * ct + lc) * CDIM + ks * 32 + 8 * lg);
            pacc[ct] = __builtin_amdgcn_mfma_f32_16x16x32_bf16(af[ks], bw, pacc[ct], 0, 0, 0);
        }
    }

#pragma unroll
    for (int ct = 0; ct < 12; ++ct) {
        const int c = 16 * ct + lc;
        const float pb = proj_b[c];
#pragma unroll
        for (int r = 0; r < 4; ++r) {
            const int i = 16 * wv + 4 * lg + r;
            if (i < NTOK)
                out[(size_t)b * (NTOK * CDIM) + i * CDIM + c] = pacc[ct][r] + pb;
        }
    }
}

extern "C" void kernel_launch(void* const* d_in, const int* in_sizes, int n_in,
                              void* d_out, int out_size, void* d_ws, size_t ws_size,
                              hipStream_t stream) {
    const float* qkv        = (const float*)d_in[0];
    const int*   rpi        = (const int*)d_in[1];
    const float* mask       = (const float*)d_in[2];
    const float* bias_table = (const float*)d_in[3];
    const float* proj_w     = (const float*)d_in[4];
    const float* proj_b     = (const float*)d_in[5];
    float* out = (float*)d_out;
    u16* wb = (u16*)d_ws;  // bf16 copy of proj_w (73728 B)

    const int nblk = in_sizes[0] / (NTOK * 3 * CDIM);  // 8192 windows

    build_wb<<<(CDIM * CDIM + 255) / 256, 256, 0, stream>>>(proj_w, wb);
    swin_fused<<<nblk, 256, 0, stream>>>(qkv, rpi, mask, bias_table, wb, proj_b, out);
}

// Round 9
// 561.445 us; speedup vs baseline: 1.9852x; 1.0678x over previous
//
#include <hip/hip_runtime.h>

#define NH 6
#define NTOK 49
#define CDIM 192
#define NWIN 1024
#define SCALE 0.17677669529663687f

typedef __bf16 bf16x8 __attribute__((ext_vector_type(8)));
typedef float f32x4 __attribute__((ext_vector_type(4)));
typedef unsigned short u16;
typedef unsigned int u32;

__device__ __forceinline__ u16 bfr(float x) { return __builtin_bit_cast(u16, (__bf16)x); }

__global__ void build_wb(const float* __restrict__ w, u16* __restrict__ wb) {
    int i = blockIdx.x * 256 + threadIdx.x;
    if (i < CDIM * CDIM) wb[i] = bfr(w[i]);
}

// Fused window attention + proj. One block per window, 256 thr = 4 waves.
// Swapped QK^T: acc = mfma(K_frag, Q_frag) = S^T, so each lane holds one
// q-row (q = 16wv+lc) with k = 16t+4lg+r; row softmax = local 16-reg tree +
// 2 shfl_xor(16,32) for max and sum. P-store packs 4 k-adjacent values into
// one 8B ushort4. R9 fix vs R8: k_s pad rows 49..63 are ZEROED once --
// additive -1e30 masking does NOT kill NaN from uninitialized LDS (R8 bug);
// with K=0 the masked entries are finite and exp() flushes them to 0.
__global__ __launch_bounds__(256, 4)
void swin_fused(const float* __restrict__ qkv, const int* __restrict__ rpi,
                const float* __restrict__ mask, const float* __restrict__ bias_table,
                const u16* __restrict__ wb, const float* __restrict__ proj_b,
                float* __restrict__ out) {
    __shared__ u16 k_s[64][40];   // K bf16; pad rows zeroed once
    __shared__ u16 vT_s[32][72];  // V^T bf16 [d][n]; pad cols zeroed once
    __shared__ u16 p_s[64][72];   // P then x_h; wave-private 16-row stripes

    const int tid = threadIdx.x;
    const int b = blockIdx.x;
    const int wn = b & (NWIN - 1);
    const int wv = tid >> 6;
    const int lane = tid & 63;
    const int lg = lane >> 4;
    const int lc = lane & 15;

    const float* qkvb = qkv + (size_t)b * (NTOK * 3 * CDIM);
    const float* mrow = mask + (size_t)wn * (NTOK * NTOK);
    const f32x4 fzero = {0.f, 0.f, 0.f, 0.f};

    // staging distribution: item idx in [0,392): n=idx>>3, f=idx&7
    const int n0 = tid >> 3, f0 = tid & 7;
    const bool s1 = tid < 136;
    const int n1 = (tid + 256) >> 3, f1 = (tid + 256) & 7;
    const float* kb0 = qkvb + n0 * 576 + CDIM + f0 * 4;
    const float* vb0 = qkvb + n0 * 576 + 2 * CDIM + f0 * 4;
    const float* kb1 = qkvb + n1 * 576 + CDIM + f1 * 4;
    const float* vb1 = qkvb + n1 * 576 + 2 * CDIM + f1 * 4;

    // per-lane Q row pointer (clamped; pad rows produce finite garbage only)
    const int qrow = (16 * wv + lc < NTOK) ? 16 * wv + lc : NTOK - 1;
    const float* qptr = qkvb + (size_t)qrow * 576 + 8 * lg;

    // ---- issue h=0 loads (latency overlaps setup below) ----
    float4 kp0 = *reinterpret_cast<const float4*>(kb0);
    float4 vp0 = *reinterpret_cast<const float4*>(vb0);
    float4 kp1 = {0, 0, 0, 0}, vp1 = {0, 0, 0, 0};
    if (s1) {
        kp1 = *reinterpret_cast<const float4*>(kb1);
        vp1 = *reinterpret_cast<const float4*>(vb1);
    }
    float4 qfA = *reinterpret_cast<const float4*>(qptr);
    float4 qfB = *reinterpret_cast<const float4*>(qptr + 4);

    // ---- per-lane (q = 16wv+lc, k = 16t+4lg+r): bias offsets + mask adds ----
    int bofs[4][4];
    float maddf[4][4];
    {
        const int i = 16 * wv + lc;
#pragma unroll
        for (int t = 0; t < 4; ++t)
#pragma unroll
            for (int r = 0; r < 4; ++r) {
                const int j = 16 * t + 4 * lg + r;
                const bool valid = (i < NTOK) && (j < NTOK);
                const int ij = valid ? i * NTOK + j : 0;
                bofs[t][r] = rpi[ij] * NH;
                maddf[t][r] = valid ? mrow[ij] : -1e30f;
            }
    }

    // ---- zero pads once: vT cols 49..63, k_s rows 49..63 (NaN sources) ----
    for (int idx = tid; idx < 512; idx += 256) {
        const int d = idx >> 4, m = idx & 15;
        if (m) vT_s[d][48 + m] = 0;
    }
    for (int idx = tid; idx < 600; idx += 256) {
        const int rr = idx / 40, cc = idx % 40;
        k_s[49 + rr][cc] = 0;
    }

    // ---- stage h=0 K and V ----
    {
        ushort4 ko;
        ko.x = bfr(kp0.x); ko.y = bfr(kp0.y); ko.z = bfr(kp0.z); ko.w = bfr(kp0.w);
        *reinterpret_cast<ushort4*>(&k_s[n0][f0 * 4]) = ko;
        const int d0 = f0 * 4;
        vT_s[d0 + 0][n0] = bfr(vp0.x); vT_s[d0 + 1][n0] = bfr(vp0.y);
        vT_s[d0 + 2][n0] = bfr(vp0.z); vT_s[d0 + 3][n0] = bfr(vp0.w);
        if (s1) {
            ushort4 k1;
            k1.x = bfr(kp1.x); k1.y = bfr(kp1.y); k1.z = bfr(kp1.z); k1.w = bfr(kp1.w);
            *reinterpret_cast<ushort4*>(&k_s[n1][f1 * 4]) = k1;
            const int d1 = f1 * 4;
            vT_s[d1 + 0][n1] = bfr(vp1.x); vT_s[d1 + 1][n1] = bfr(vp1.y);
            vT_s[d1 + 2][n1] = bfr(vp1.z); vT_s[d1 + 3][n1] = bfr(vp1.w);
        }
    }
    __syncthreads();

    bf16x8 af[NH];  // x_h A-fragments (static index via full unroll)

#pragma unroll
    for (int h = 0; h < NH; ++h) {
        // ---- issue K/V stage-loads for h+1 ----
        if (h + 1 < NH) {
            kp0 = *reinterpret_cast<const float4*>(kb0 + (h + 1) * 32);
            vp0 = *reinterpret_cast<const float4*>(vb0 + (h + 1) * 32);
            if (s1) {
                kp1 = *reinterpret_cast<const float4*>(kb1 + (h + 1) * 32);
                vp1 = *reinterpret_cast<const float4*>(vb1 + (h + 1) * 32);
            }
        }

        // ---- Q fragment from prefetched regs ----
        bf16x8 aq;
        aq[0] = (__bf16)(qfA.x * SCALE); aq[1] = (__bf16)(qfA.y * SCALE);
        aq[2] = (__bf16)(qfA.z * SCALE); aq[3] = (__bf16)(qfA.w * SCALE);
        aq[4] = (__bf16)(qfB.x * SCALE); aq[5] = (__bf16)(qfB.y * SCALE);
        aq[6] = (__bf16)(qfB.z * SCALE); aq[7] = (__bf16)(qfB.w * SCALE);
        if (h + 1 < NH) {
            qfA = *reinterpret_cast<const float4*>(qptr + (h + 1) * 32);
            qfB = *reinterpret_cast<const float4*>(qptr + (h + 1) * 32 + 4);
        }

        // ---- bias gather (L1-resident 4KB table), overlaps MFMA issue ----
        float bias_v[4][4];
#pragma unroll
        for (int t = 0; t < 4; ++t)
#pragma unroll
            for (int r = 0; r < 4; ++r)
                bias_v[t][r] = bias_table[bofs[t][r] + h];

        // ---- swapped QK^T: acc[t] = S^T tile -> lane holds q-row 16wv+lc,
        //      k = 16t + 4lg + r ----
        bf16x8 bk[4];
#pragma unroll
        for (int t = 0; t < 4; ++t)
            bk[t] = *reinterpret_cast<const bf16x8*>(&k_s[16 * t + lc][8 * lg]);
        f32x4 acc[4];
#pragma unroll
        for (int t = 0; t < 4; ++t)
            acc[t] = __builtin_amdgcn_mfma_f32_16x16x32_bf16(bk[t], aq, fzero, 0, 0, 0);

        // ---- softmax: lane-local row tree + 2 shfl for max and sum ----
        float vals[4][4];
#pragma unroll
        for (int t = 0; t < 4; ++t)
#pragma unroll
            for (int r = 0; r < 4; ++r)
                vals[t][r] = acc[t][r] + bias_v[t][r] + maddf[t][r];

        float mx[4];
#pragma unroll
        for (int t = 0; t < 4; ++t)
            mx[t] = fmaxf(fmaxf(vals[t][0], vals[t][1]), fmaxf(vals[t][2], vals[t][3]));
        float m = fmaxf(fmaxf(mx[0], mx[1]), fmaxf(mx[2], mx[3]));
        m = fmaxf(m, __shfl_xor(m, 16));
        m = fmaxf(m, __shfl_xor(m, 32));

        float e[4][4];
        float s = 0.f;
#pragma unroll
        for (int t = 0; t < 4; ++t) {
            float st = 0.f;
#pragma unroll
            for (int r = 0; r < 4; ++r) { e[t][r] = __expf(vals[t][r] - m); st += e[t][r]; }
            s += st;
        }
        s += __shfl_xor(s, 16);
        s += __shfl_xor(s, 32);
        const float rs = 1.0f / s;

        // ---- packed P store: 4x 8B per lane (k-adjacent r values) ----
        {
            u16* prow = &p_s[16 * wv + lc][4 * lg];
#pragma unroll
            for (int t = 0; t < 4; ++t) {
                ushort4 pk;
                pk.x = bfr(e[t][0] * rs); pk.y = bfr(e[t][1] * rs);
                pk.z = bfr(e[t][2] * rs); pk.w = bfr(e[t][3] * rs);
                *reinterpret_cast<ushort4*>(prow + 16 * t) = pk;
            }
        }

        // ---- PV: x_h[16x32] per wave (p_s rows wave-private) ----
        f32x4 xacc[2] = {fzero, fzero};
#pragma unroll
        for (int ks = 0; ks < 2; ++ks) {
            const bf16x8 pa = *reinterpret_cast<const bf16x8*>(&p_s[16 * wv + lc][32 * ks + 8 * lg]);
#pragma unroll
            for (int ct = 0; ct < 2; ++ct) {
                const bf16x8 vv = *reinterpret_cast<const bf16x8*>(&vT_s[16 * ct + lc][32 * ks + 8 * lg]);
                xacc[ct] = __builtin_amdgcn_mfma_f32_16x16x32_bf16(pa, vv, xacc[ct], 0, 0, 0);
            }
        }

        // ---- x_h C-layout -> A-fragment via wave-private p_s stripe ----
#pragma unroll
        for (int ct = 0; ct < 2; ++ct)
#pragma unroll
            for (int r = 0; r < 4; ++r)
                p_s[16 * wv + 4 * lg + r][16 * ct + lc] = bfr(xacc[ct][r]);
        af[h] = *reinterpret_cast<const bf16x8*>(&p_s[16 * wv + lc][8 * lg]);

        // ---- stage h+1 K/V ----
        if (h + 1 < NH) {
            __syncthreads();  // all waves done reading k_s/vT of head h
            ushort4 ko;
            ko.x = bfr(kp0.x); ko.y = bfr(kp0.y); ko.z = bfr(kp0.z); ko.w = bfr(kp0.w);
            *reinterpret_cast<ushort4*>(&k_s[n0][f0 * 4]) = ko;
            const int d0 = f0 * 4;
            vT_s[d0 + 0][n0] = bfr(vp0.x); vT_s[d0 + 1][n0] = bfr(vp0.y);
            vT_s[d0 + 2][n0] = bfr(vp0.z); vT_s[d0 + 3][n0] = bfr(vp0.w);
            if (s1) {
                ushort4 k1;
                k1.x = bfr(kp1.x); k1.y = bfr(kp1.y); k1.z = bfr(kp1.z); k1.w = bfr(kp1.w);
                *reinterpret_cast<ushort4*>(&k_s[n1][f1 * 4]) = k1;
                const int d1 = f1 * 4;
                vT_s[d1 + 0][n1] = bfr(vp1.x); vT_s[d1 + 1][n1] = bfr(vp1.y);
                vT_s[d1 + 2][n1] = bfr(vp1.z); vT_s[d1 + 3][n1] = bfr(vp1.w);
            }
            __syncthreads();  // k_s/vT for h+1 ready
        }
    }

    // ---- proj tail: out rows 16wv.., all 192 cols; pacc live only here ----
    f32x4 pacc[12];
#pragma unroll
    for (int ct = 0; ct < 12; ++ct) pacc[ct] = fzero;

#pragma unroll
    for (int ks = 0; ks < NH; ++ks) {
#pragma unroll
        for (int ct = 0; ct < 12; ++ct) {
            const bf16x8 bw = *reinterpret_cast<const bf16x8*>(wb + (16 * ct + lc) * CDIM + ks * 32 + 8 * lg);
            pacc[ct] = __builtin_amdgcn_mfma_f32_16x16x32_bf16(af[ks], bw, pacc[ct], 0, 0, 0);
        }
    }

#pragma unroll
    for (int ct = 0; ct < 12; ++ct) {
        const int c = 16 * ct + lc;
        const float pb = proj_b[c];
#pragma unroll
        for (int r = 0; r < 4; ++r) {
            const int i = 16 * wv + 4 * lg + r;
            if (i < NTOK)
                out[(size_t)b * (NTOK * CDIM) + i * CDIM + c] = pacc[ct][r] + pb;
        }
    }
}

extern "C" void kernel_launch(void* const* d_in, const int* in_sizes, int n_in,
                              void* d_out, int out_size, void* d_ws, size_t ws_size,
                              hipStream_t stream) {
    const float* qkv        = (const float*)d_in[0];
    const int*   rpi        = (const int*)d_in[1];
    const float* mask       = (const float*)d_in[2];
    const float* bias_table = (const float*)d_in[3];
    const float* proj_w     = (const float*)d_in[4];
    const float* proj_b     = (const float*)d_in[5];
    float* out = (float*)d_out;
    u16* wb = (u16*)d_ws;  // bf16 copy of proj_w (73728 B)

    const int nblk = in_sizes[0] / (NTOK * 3 * CDIM);  // 8192 windows

    build_wb<<<(CDIM * CDIM + 255) / 256, 256, 0, stream>>>(proj_w, wb);
    swin_fused<<<nblk, 256, 0, stream>>>(qkv, rpi, mask, bias_table, wb, proj_b, out);
}